// Round 7
// baseline (85.520 us; speedup 1.0000x reference)
//
#include <hip/hip_runtime.h>

#define NB 2
#define SQL 256
#define NH 16
#define HD 64
#define EMB 1024

typedef unsigned short ushortT;
typedef unsigned int uintT;

// log2(e) / sqrt(EMBED): folded into Wq so softmax = 2^(q*k)
__device__ __constant__ float kQSCALE = 1.4426950408889634f / 32.0f;

__device__ __forceinline__ float fexp2(float x) { return __builtin_amdgcn_exp2f(x); }
__device__ __forceinline__ float frcp(float x)  { return __builtin_amdgcn_rcpf(x); }

__device__ __forceinline__ ushortT f2bf(float x) {
    uintT u = __float_as_uint(x);
    u += 0x7fffu + ((u >> 16) & 1u);        // RNE
    return (ushortT)(u >> 16);
}
// unpack 8 bf16 (element order = memory order) to f32
__device__ __forceinline__ void unpk8(uint4 u, float* f) {
    f[0] = __uint_as_float(u.x << 16); f[1] = __uint_as_float(u.x & 0xffff0000u);
    f[2] = __uint_as_float(u.y << 16); f[3] = __uint_as_float(u.y & 0xffff0000u);
    f[4] = __uint_as_float(u.z << 16); f[5] = __uint_as_float(u.z & 0xffff0000u);
    f[6] = __uint_as_float(u.w << 16); f[7] = __uint_as_float(u.w & 0xffff0000u);
}

// ---------------------------------------------------------------------------
// Kernel 0: out = bias broadcast; AO = 0. Replaces memset + reduce epilogue.
// ---------------------------------------------------------------------------
__global__ __launch_bounds__(256) void init_kernel(
    const float* __restrict__ bo,
    float* __restrict__ AO,
    float* __restrict__ out)
{
    const int i = blockIdx.x * 256 + threadIdx.x;   // 131072 float4s
    const float4 b = ((const float4*)bo)[i & 255];
    ((float4*)out)[i] = b;
    ((float4*)AO)[i]  = make_float4(0.f, 0.f, 0.f, 0.f);
}

// ---------------------------------------------------------------------------
// Kernel 1: q/k/v projections -> bf16. TWO blocks per (n,s), each computing
// 32 of 64 e-outputs. Output element order [ns][e*16+h]. Wq pre-scaled.
// ---------------------------------------------------------------------------
__global__ __launch_bounds__(256) void qkv_kernel(
    const float* __restrict__ x,
    const float* __restrict__ Wq,
    const float* __restrict__ Wk,
    const float* __restrict__ Wv,
    ushortT* __restrict__ Q,
    ushortT* __restrict__ K,
    ushortT* __restrict__ V)
{
    __shared__ float wq[32 * 68];
    __shared__ float wk[32 * 68];
    __shared__ float wv[32 * 68];
    __shared__ float xs[16 * 68];

    const int tid  = threadIdx.x;
    const int ns   = blockIdx.x >> 1;
    const int half = blockIdx.x & 1;

    {
        const int h  = tid >> 4;
        const int d0 = (tid & 15) * 4;
        const float4 a = ((const float4*)(x + (size_t)ns * EMB))[tid];
        *(float4*)&xs[h * 68 + d0] = a;
    }
#pragma unroll
    for (int j = 0; j < 2; ++j) {
        const int f4 = j * 256 + tid;
        const int e  = f4 >> 4;
        const int d4 = f4 & 15;
        const int g  = half * 512 + f4;
        float4 a = ((const float4*)Wq)[g];
        a.x *= kQSCALE; a.y *= kQSCALE; a.z *= kQSCALE; a.w *= kQSCALE;
        *(float4*)&wq[e * 68 + d4 * 4] = a;
        *(float4*)&wk[e * 68 + d4 * 4] = ((const float4*)Wk)[g];
        *(float4*)&wv[e * 68 + d4 * 4] = ((const float4*)Wv)[g];
    }
    __syncthreads();

    const int el = tid >> 3;
    const int h0 = (tid & 7) * 2;

    float aq[2] = {0.f, 0.f}, ak[2] = {0.f, 0.f}, av[2] = {0.f, 0.f};

#pragma unroll
    for (int d4 = 0; d4 < 16; ++d4) {
        const float4 wqv = *(const float4*)&wq[el * 68 + d4 * 4];
        const float4 wkv = *(const float4*)&wk[el * 68 + d4 * 4];
        const float4 wvv = *(const float4*)&wv[el * 68 + d4 * 4];
#pragma unroll
        for (int hh = 0; hh < 2; ++hh) {
            const float4 xv = *(const float4*)&xs[(h0 + hh) * 68 + d4 * 4];
            aq[hh] = fmaf(xv.x, wqv.x, fmaf(xv.y, wqv.y, fmaf(xv.z, wqv.z, fmaf(xv.w, wqv.w, aq[hh]))));
            ak[hh] = fmaf(xv.x, wkv.x, fmaf(xv.y, wkv.y, fmaf(xv.z, wkv.z, fmaf(xv.w, wkv.w, ak[hh]))));
            av[hh] = fmaf(xv.x, wvv.x, fmaf(xv.y, wvv.y, fmaf(xv.z, wvv.z, fmaf(xv.w, wvv.w, av[hh]))));
        }
    }
    const size_t off = (size_t)ns * EMB + half * 512 + 2 * tid;   // even
    *(ushort2*)&Q[off] = make_ushort2(f2bf(aq[0]), f2bf(aq[1]));
    *(ushort2*)&K[off] = make_ushort2(f2bf(ak[0]), f2bf(ak[1]));
    *(ushort2*)&V[off] = make_ushort2(f2bf(av[0]), f2bf(av[1]));
}

// ---------------------------------------------------------------------------
// Kernel 2: fused energy -> softmax(h) -> sum(t). bf16 Q/K/V.
// LANE-LOCAL softmax: lane l owns ALL 16 h of channel e=l (two consecutive
// uint4 per row). h-sum = 15 local adds, NO cross-lane, no DS pipe in the
// critical path (round-6 lesson: shfl latency serialized the chain).
// Wave = 2 s-streams x full e; block = 8 s; grid = 2n*32sg*16tc = 1024
// (4 blocks/CU = exactly 4 waves/SIMD for the ~110-reg state).
// Unroll-2 ping/pong: no register rotation, no tail branch (the one-iter
// over-read lands in the adjacent workspace buffer - safe, discarded).
// ---------------------------------------------------------------------------
#define ATTN_COMPUTE(KX0, KX1, VX0, VX1)                                      \
    {                                                                         \
        float ku[16], vu[16], p[16];                                          \
        unpk8(KX0, ku); unpk8(KX1, ku + 8);                                   \
        unpk8(VX0, vu); unpk8(VX1, vu + 8);                                   \
        _Pragma("unroll")                                                     \
        for (int i = 0; i < 16; ++i) p[i] = fexp2(qa0[i] * ku[i]);            \
        float u = (((p[0]+p[1])+(p[2]+p[3])) + ((p[4]+p[5])+(p[6]+p[7])))     \
                + (((p[8]+p[9])+(p[10]+p[11])) + ((p[12]+p[13])+(p[14]+p[15])));\
        float rs = frcp(u);                                                   \
        _Pragma("unroll")                                                     \
        for (int i = 0; i < 16; ++i) acc0[i] = fmaf(p[i] * rs, vu[i], acc0[i]);\
        _Pragma("unroll")                                                     \
        for (int i = 0; i < 16; ++i) p[i] = fexp2(qa1[i] * ku[i]);            \
        u = (((p[0]+p[1])+(p[2]+p[3])) + ((p[4]+p[5])+(p[6]+p[7])))           \
          + (((p[8]+p[9])+(p[10]+p[11])) + ((p[12]+p[13])+(p[14]+p[15])));    \
        rs = frcp(u);                                                         \
        _Pragma("unroll")                                                     \
        for (int i = 0; i < 16; ++i) acc1[i] = fmaf(p[i] * rs, vu[i], acc1[i]);\
    }

__global__ __launch_bounds__(256, 4) void attn_kernel(
    const ushortT* __restrict__ Q,
    const ushortT* __restrict__ K,
    const ushortT* __restrict__ V,
    float* __restrict__ AO)
{
    const int b    = blockIdx.x;        // 2n * 32sg * 16tc = 1024
    const int tc   = b & 15;
    const int sg   = (b >> 4) & 31;
    const int n    = b >> 9;
    const int wave = threadIdx.x >> 6;
    const int l    = threadIdx.x & 63;  // = e (channel)
    const int s0   = sg * 8 + wave * 2;
    const int t0   = tc * 16;

    float qa0[16], qa1[16];
    {
        const uint4* qp = (const uint4*)(Q + (size_t)(n * SQL + s0) * EMB) + 2 * l;
        unpk8(qp[0], qa0);   unpk8(qp[1], qa0 + 8);
        unpk8(qp[128], qa1); unpk8(qp[129], qa1 + 8);   // next s row
    }
    float acc0[16], acc1[16];
#pragma unroll
    for (int i = 0; i < 16; ++i) { acc0[i] = 0.f; acc1[i] = 0.f; }

    const uint4* kp = (const uint4*)(K + (size_t)(n * SQL + t0) * EMB) + 2 * l;
    const uint4* vp = (const uint4*)(V + (size_t)(n * SQL + t0) * EMB) + 2 * l;

    uint4 ka0 = kp[0], ka1 = kp[1];
    uint4 va0 = vp[0], va1 = vp[1];

#pragma unroll
    for (int tt = 0; tt < 16; tt += 2) {
        const uint4 kb0 = kp[128], kb1 = kp[129];
        const uint4 vb0 = vp[128], vb1 = vp[129];
        kp += 256; vp += 256;
        ATTN_COMPUTE(ka0, ka1, va0, va1);
        ka0 = kp[0]; ka1 = kp[1];       // t+2 (last iter over-reads: safe)
        va0 = vp[0]; va1 = vp[1];
        ATTN_COMPUTE(kb0, kb1, vb0, vb1);
    }

    // lane l = e, element h: AO channel = h*64 + e
    float* ao0 = AO + (size_t)(n * SQL + s0) * EMB + l;
    float* ao1 = ao0 + EMB;
#pragma unroll
    for (int c = 0; c < 16; ++c) {
        atomicAdd(ao0 + 64 * c, acc0[c]);
        atomicAdd(ao1 + 64 * c, acc1[c]);
    }
}

// ---------------------------------------------------------------------------
// Kernel 3: out += AO @ Wo^T (f32 vector GEMM). 64r x 32j tile, k-split 4.
// Grid = 8rt * 32jt * 4kc = 1024 blocks. atomicAdd into bias-initialized out
// (replaces partials buffer + reduce kernel).
// ---------------------------------------------------------------------------
__global__ __launch_bounds__(256) void proj_kernel(
    const float* __restrict__ A,
    const float* __restrict__ Wo,
    float* __restrict__ out)
{
    __shared__ float As[32][68];
    __shared__ float Ws[32][36];

    const int b  = blockIdx.x;
    const int kc = b & 3;
    const int jt = (b >> 2) & 31;
    const int rt = b >> 7;
    const int tid = threadIdx.x;
    const int tx = tid & 15;
    const int ty = tid >> 4;
    const int r0 = rt * 64, j0 = jt * 32, k0 = kc * 256;

    float2 c2[4];
#pragma unroll
    for (int i = 0; i < 4; ++i) c2[i] = make_float2(0.f, 0.f);

    for (int kt = 0; kt < 8; ++kt) {
        const int kb = k0 + kt * 32;
        __syncthreads();
#pragma unroll
        for (int it = 0; it < 2; ++it) {
            const int f   = it * 256 + tid;
            const int row = f >> 3;
            const int kq  = f & 7;
            const float4 a = *(const float4*)&A[(size_t)(r0 + row) * EMB + kb + kq * 4];
            As[kq * 4 + 0][row] = a.x;
            As[kq * 4 + 1][row] = a.y;
            As[kq * 4 + 2][row] = a.z;
            As[kq * 4 + 3][row] = a.w;
        }
        {
            const int row = tid >> 3;
            const int kq  = tid & 7;
            const float4 w = *(const float4*)&Wo[(size_t)(j0 + row) * EMB + kb + kq * 4];
            Ws[kq * 4 + 0][row] = w.x;
            Ws[kq * 4 + 1][row] = w.y;
            Ws[kq * 4 + 2][row] = w.z;
            Ws[kq * 4 + 3][row] = w.w;
        }
        __syncthreads();
#pragma unroll
        for (int kk = 0; kk < 32; ++kk) {
            const float4 a4 = *(const float4*)&As[kk][ty * 4];
            const float2 w2 = *(const float2*)&Ws[kk][tx * 2];
            c2[0].x = fmaf(a4.x, w2.x, c2[0].x); c2[0].y = fmaf(a4.x, w2.y, c2[0].y);
            c2[1].x = fmaf(a4.y, w2.x, c2[1].x); c2[1].y = fmaf(a4.y, w2.y, c2[1].y);
            c2[2].x = fmaf(a4.z, w2.x, c2[2].x); c2[2].y = fmaf(a4.z, w2.y, c2[2].y);
            c2[3].x = fmaf(a4.w, w2.x, c2[3].x); c2[3].y = fmaf(a4.w, w2.y, c2[3].y);
        }
    }

#pragma unroll
    for (int rr = 0; rr < 4; ++rr) {
        float* o = out + (size_t)(r0 + ty * 4 + rr) * EMB + j0 + tx * 2;
        atomicAdd(o,     c2[rr].x);
        atomicAdd(o + 1, c2[rr].y);
    }
}

extern "C" void kernel_launch(void* const* d_in, const int* in_sizes, int n_in,
                              void* d_out, int out_size, void* d_ws, size_t ws_size,
                              hipStream_t stream)
{
    const float* x  = (const float*)d_in[0];
    const float* Wq = (const float*)d_in[1];
    const float* Wk = (const float*)d_in[2];
    const float* Wv = (const float*)d_in[3];
    const float* Wo = (const float*)d_in[4];
    const float* bo = (const float*)d_in[5];

    float* ws = (float*)d_ws;
    ushortT* Q = (ushortT*)ws;              // 524288 bf16 = 1 MB
    ushortT* K = (ushortT*)(ws + 262144);   // 1 MB
    ushortT* V = (ushortT*)(ws + 524288);   // 1 MB
    float* AO  = ws + 786432;               // 524288 f32 = 2 MB

    init_kernel<<<512, 256, 0, stream>>>(bo, AO, (float*)d_out);
    qkv_kernel<<<1024, 256, 0, stream>>>(x, Wq, Wk, Wv, Q, K, V);
    attn_kernel<<<1024, 256, 0, stream>>>(Q, K, V, AO);
    proj_kernel<<<1024, 256, 0, stream>>>(AO, Wo, (float*)d_out);
}

// Round 8
// 69.682 us; speedup vs baseline: 1.2273x; 1.2273x over previous
//
#include <hip/hip_runtime.h>

#define NB 2
#define SQL 256
#define NH 16
#define HD 64
#define EMB 1024

typedef unsigned short ushortT;
typedef unsigned int uintT;
typedef __attribute__((ext_vector_type(8))) short bf16x8;
typedef __attribute__((ext_vector_type(4))) float f32x4;

// log2(e) / sqrt(EMBED): folded into Wq so softmax = 2^(q*k)
__device__ __constant__ float kQSCALE = 1.4426950408889634f / 32.0f;

__device__ __forceinline__ float fexp2(float x) { return __builtin_amdgcn_exp2f(x); }
__device__ __forceinline__ float frcp(float x)  { return __builtin_amdgcn_rcpf(x); }

__device__ __forceinline__ ushortT f2bf(float x) {
    uintT u = __float_as_uint(x);
    u += 0x7fffu + ((u >> 16) & 1u);        // RNE
    return (ushortT)(u >> 16);
}
// unpack 8 bf16 (element order = memory order) to f32
__device__ __forceinline__ void unpk8(uint4 u, float* f) {
    f[0] = __uint_as_float(u.x << 16); f[1] = __uint_as_float(u.x & 0xffff0000u);
    f[2] = __uint_as_float(u.y << 16); f[3] = __uint_as_float(u.y & 0xffff0000u);
    f[4] = __uint_as_float(u.z << 16); f[5] = __uint_as_float(u.z & 0xffff0000u);
    f[6] = __uint_as_float(u.w << 16); f[7] = __uint_as_float(u.w & 0xffff0000u);
}

// ---------------------------------------------------------------------------
// Kernel 0: out = bias broadcast; AO = 0.
// ---------------------------------------------------------------------------
__global__ __launch_bounds__(256) void init_kernel(
    const float* __restrict__ bo,
    float* __restrict__ AO,
    float* __restrict__ out)
{
    const int i = blockIdx.x * 256 + threadIdx.x;   // 131072 float4s
    const float4 b = ((const float4*)bo)[i & 255];
    ((float4*)out)[i] = b;
    ((float4*)AO)[i]  = make_float4(0.f, 0.f, 0.f, 0.f);
}

// ---------------------------------------------------------------------------
// Kernel 1: q/k/v projections -> bf16. TWO blocks per (n,s), each computing
// 32 of 64 e-outputs. Output element order [ns][e*16+h]. Wq pre-scaled.
// ---------------------------------------------------------------------------
__global__ __launch_bounds__(256) void qkv_kernel(
    const float* __restrict__ x,
    const float* __restrict__ Wq,
    const float* __restrict__ Wk,
    const float* __restrict__ Wv,
    ushortT* __restrict__ Q,
    ushortT* __restrict__ K,
    ushortT* __restrict__ V)
{
    __shared__ float wq[32 * 68];
    __shared__ float wk[32 * 68];
    __shared__ float wv[32 * 68];
    __shared__ float xs[16 * 68];

    const int tid  = threadIdx.x;
    const int ns   = blockIdx.x >> 1;
    const int half = blockIdx.x & 1;

    {
        const int h  = tid >> 4;
        const int d0 = (tid & 15) * 4;
        const float4 a = ((const float4*)(x + (size_t)ns * EMB))[tid];
        *(float4*)&xs[h * 68 + d0] = a;
    }
#pragma unroll
    for (int j = 0; j < 2; ++j) {
        const int f4 = j * 256 + tid;
        const int e  = f4 >> 4;
        const int d4 = f4 & 15;
        const int g  = half * 512 + f4;
        float4 a = ((const float4*)Wq)[g];
        a.x *= kQSCALE; a.y *= kQSCALE; a.z *= kQSCALE; a.w *= kQSCALE;
        *(float4*)&wq[e * 68 + d4 * 4] = a;
        *(float4*)&wk[e * 68 + d4 * 4] = ((const float4*)Wk)[g];
        *(float4*)&wv[e * 68 + d4 * 4] = ((const float4*)Wv)[g];
    }
    __syncthreads();

    const int el = tid >> 3;
    const int h0 = (tid & 7) * 2;

    float aq[2] = {0.f, 0.f}, ak[2] = {0.f, 0.f}, av[2] = {0.f, 0.f};

#pragma unroll
    for (int d4 = 0; d4 < 16; ++d4) {
        const float4 wqv = *(const float4*)&wq[el * 68 + d4 * 4];
        const float4 wkv = *(const float4*)&wk[el * 68 + d4 * 4];
        const float4 wvv = *(const float4*)&wv[el * 68 + d4 * 4];
#pragma unroll
        for (int hh = 0; hh < 2; ++hh) {
            const float4 xv = *(const float4*)&xs[(h0 + hh) * 68 + d4 * 4];
            aq[hh] = fmaf(xv.x, wqv.x, fmaf(xv.y, wqv.y, fmaf(xv.z, wqv.z, fmaf(xv.w, wqv.w, aq[hh]))));
            ak[hh] = fmaf(xv.x, wkv.x, fmaf(xv.y, wkv.y, fmaf(xv.z, wkv.z, fmaf(xv.w, wkv.w, ak[hh]))));
            av[hh] = fmaf(xv.x, wvv.x, fmaf(xv.y, wvv.y, fmaf(xv.z, wvv.z, fmaf(xv.w, wvv.w, av[hh]))));
        }
    }
    const size_t off = (size_t)ns * EMB + half * 512 + 2 * tid;   // even
    *(ushort2*)&Q[off] = make_ushort2(f2bf(aq[0]), f2bf(aq[1]));
    *(ushort2*)&K[off] = make_ushort2(f2bf(ak[0]), f2bf(ak[1]));
    *(ushort2*)&V[off] = make_ushort2(f2bf(av[0]), f2bf(av[1]));
}

// ---------------------------------------------------------------------------
// Kernel 2: fused energy -> softmax(h) -> sum(t). Round-6 version (measured
// best: 40.2us). Wave tile: 2 s x half e-range (eh); lane = one uint4 (8
// bf16); h-sum = 7 local adds + 1 shfl_xor(1); reg double-buffer on K/V.
// Grid: 2n * 32st(8s) * 2eh * 16tc = 2048 blocks.
// ---------------------------------------------------------------------------
__global__ __attribute__((amdgpu_waves_per_eu(4, 8))) __launch_bounds__(256)
void attn_kernel(
    const ushortT* __restrict__ Q,
    const ushortT* __restrict__ K,
    const ushortT* __restrict__ V,
    float* __restrict__ AO)
{
    const int b    = blockIdx.x;
    const int tc   = b & 15;
    const int eh   = (b >> 4) & 1;
    const int st   = (b >> 5) & 31;
    const int n    = b >> 10;
    const int wave = threadIdx.x >> 6;
    const int l    = threadIdx.x & 63;
    const int s0   = st * 8 + wave * 2;
    const int t0   = tc * 16;

    float qa0[8], qa1[8];
    {
        const uint4* qp = (const uint4*)(Q + (size_t)(n * SQL + s0) * EMB + 512 * eh) + l;
        unpk8(qp[0], qa0);
        unpk8(qp[128], qa1);   // next s row = 1024 ushorts = 128 uint4
    }

    float a0[8], a1[8];
#pragma unroll
    for (int i = 0; i < 8; ++i) { a0[i] = 0.f; a1[i] = 0.f; }

    const uint4* kp = (const uint4*)(K + (size_t)(n * SQL + t0) * EMB + 512 * eh) + l;
    const uint4* vp = (const uint4*)(V + (size_t)(n * SQL + t0) * EMB + 512 * eh) + l;

    uint4 kk = kp[0];
    uint4 vv = vp[0];
    kp += 128; vp += 128;

    for (int tt = 0; tt < 16; ++tt) {
        uint4 kn, vn;
        if (tt < 15) {                // prefetch next t (reg double-buffer)
            kn = kp[0];
            vn = vp[0];
            kp += 128; vp += 128;
        }
        float ku[8], vu[8], p0[8], p1[8];
        unpk8(kk, ku);
#pragma unroll
        for (int i = 0; i < 8; ++i) p0[i] = fexp2(qa0[i] * ku[i]);
#pragma unroll
        for (int i = 0; i < 8; ++i) p1[i] = fexp2(qa1[i] * ku[i]);
        float u0 = ((p0[0] + p0[1]) + (p0[2] + p0[3])) + ((p0[4] + p0[5]) + (p0[6] + p0[7]));
        float u1 = ((p1[0] + p1[1]) + (p1[2] + p1[3])) + ((p1[4] + p1[5]) + (p1[6] + p1[7]));
        u0 += __shfl_xor(u0, 1);
        u1 += __shfl_xor(u1, 1);
        const float rs0 = frcp(u0);
        const float rs1 = frcp(u1);
        unpk8(vv, vu);
#pragma unroll
        for (int i = 0; i < 8; ++i) {
            a0[i] = fmaf(p0[i] * rs0, vu[i], a0[i]);
            a1[i] = fmaf(p1[i] * rs1, vu[i], a1[i]);
        }
        kk = kn; vv = vn;
    }

    // element (within row) = 512eh + 8l + c  ->  e = 32eh+(l>>1), h = 8(l&1)+c
    // AO channel = h*64 + e = 512(l&1) + 64c + 32eh + (l>>1)
    float* base0 = AO + (size_t)(n * SQL + s0) * EMB + 512 * (l & 1) + 32 * eh + (l >> 1);
    float* base1 = base0 + EMB;
#pragma unroll
    for (int c = 0; c < 8; ++c) {
        atomicAdd(base0 + 64 * c, a0[c]);
        atomicAdd(base1 + 64 * c, a1[c]);
    }
}

// ---------------------------------------------------------------------------
// Kernel 3: out += AO @ Wo^T via bf16 MFMA (16x16x32). AO (f32) is converted
// to bf16 during LDS staging. 64x64 tile, 4 waves = 2x2 quadrants of 32x32,
// k-split 4 -> f32 atomicAdd into bias-initialized out.
// Fragment map (m89-verified family): A/B lane&15 = row/col, k = 8*(lane>>4)
// + e (8 contiguous bf16 -> ds_read_b128); C: col = lane&15, row =
// (lane>>4)*4 + reg. LDS rows padded to 40 bf16 (80B) -> 2-way max (free).
// Grid = 8rt * 16jt * 4kc = 512 blocks.
// ---------------------------------------------------------------------------
__global__ __launch_bounds__(256) void proj_kernel(
    const float* __restrict__ AO,
    const float* __restrict__ Wo,
    float* __restrict__ out)
{
    __shared__ ushortT As[64 * 40];
    __shared__ ushortT Bs[64 * 40];

    const int b  = blockIdx.x;
    const int kc = b & 3;
    const int jt = (b >> 2) & 15;
    const int rt = b >> 6;
    const int tid = threadIdx.x;
    const int r0 = rt * 64, j0 = jt * 64, k0 = kc * 256;

    const int w  = tid >> 6;        // wave 0..3
    const int wr = w >> 1;          // quadrant row
    const int wc = w & 1;           // quadrant col
    const int l  = tid & 63;
    const int lr = l & 15;
    const int lk = l >> 4;

    f32x4 c00 = {0.f, 0.f, 0.f, 0.f};
    f32x4 c01 = {0.f, 0.f, 0.f, 0.f};
    f32x4 c10 = {0.f, 0.f, 0.f, 0.f};
    f32x4 c11 = {0.f, 0.f, 0.f, 0.f};

    const int srow = tid >> 3;       // staging row 0..63 (two halves)
    const int skq  = tid & 7;        // k-quad

    for (int kt = 0; kt < 8; ++kt) {
        const int kb = k0 + kt * 32;
        __syncthreads();
#pragma unroll
        for (int it = 0; it < 2; ++it) {
            const int row = it * 32 + srow;
            const float4 a = *(const float4*)&AO[(size_t)(r0 + row) * EMB + kb + skq * 4];
            ushortT* da = &As[row * 40 + skq * 4];
            da[0] = f2bf(a.x); da[1] = f2bf(a.y); da[2] = f2bf(a.z); da[3] = f2bf(a.w);
            const float4 wv = *(const float4*)&Wo[(size_t)(j0 + row) * EMB + kb + skq * 4];
            ushortT* db = &Bs[row * 40 + skq * 4];
            db[0] = f2bf(wv.x); db[1] = f2bf(wv.y); db[2] = f2bf(wv.z); db[3] = f2bf(wv.w);
        }
        __syncthreads();

        const bf16x8 a0 = *(const bf16x8*)&As[(wr * 32 + lr) * 40 + lk * 8];
        const bf16x8 a1 = *(const bf16x8*)&As[(wr * 32 + 16 + lr) * 40 + lk * 8];
        const bf16x8 b0 = *(const bf16x8*)&Bs[(wc * 32 + lr) * 40 + lk * 8];
        const bf16x8 b1 = *(const bf16x8*)&Bs[(wc * 32 + 16 + lr) * 40 + lk * 8];
        c00 = __builtin_amdgcn_mfma_f32_16x16x32_bf16(a0, b0, c00, 0, 0, 0);
        c01 = __builtin_amdgcn_mfma_f32_16x16x32_bf16(a0, b1, c01, 0, 0, 0);
        c10 = __builtin_amdgcn_mfma_f32_16x16x32_bf16(a1, b0, c10, 0, 0, 0);
        c11 = __builtin_amdgcn_mfma_f32_16x16x32_bf16(a1, b1, c11, 0, 0, 0);
    }

    // C: row = (lane>>4)*4 + e, col = lane&15 (within each 16x16 fragment)
    const int rbase = r0 + wr * 32 + lk * 4;
    const int jbase = j0 + wc * 32 + lr;
#pragma unroll
    for (int e = 0; e < 4; ++e) {
        atomicAdd(&out[(size_t)(rbase + e) * EMB + jbase],           c00[e]);
        atomicAdd(&out[(size_t)(rbase + e) * EMB + jbase + 16],      c01[e]);
        atomicAdd(&out[(size_t)(rbase + 16 + e) * EMB + jbase],      c10[e]);
        atomicAdd(&out[(size_t)(rbase + 16 + e) * EMB + jbase + 16], c11[e]);
    }
}

extern "C" void kernel_launch(void* const* d_in, const int* in_sizes, int n_in,
                              void* d_out, int out_size, void* d_ws, size_t ws_size,
                              hipStream_t stream)
{
    const float* x  = (const float*)d_in[0];
    const float* Wq = (const float*)d_in[1];
    const float* Wk = (const float*)d_in[2];
    const float* Wv = (const float*)d_in[3];
    const float* Wo = (const float*)d_in[4];
    const float* bo = (const float*)d_in[5];

    float* ws = (float*)d_ws;
    ushortT* Q = (ushortT*)ws;              // 524288 bf16 = 1 MB
    ushortT* K = (ushortT*)(ws + 262144);   // 1 MB
    ushortT* V = (ushortT*)(ws + 524288);   // 1 MB
    float* AO  = ws + 786432;               // 524288 f32 = 2 MB

    init_kernel<<<512, 256, 0, stream>>>(bo, AO, (float*)d_out);
    qkv_kernel<<<1024, 256, 0, stream>>>(x, Wq, Wk, Wv, Q, K, V);
    attn_kernel<<<2048, 256, 0, stream>>>(Q, K, V, AO);
    proj_kernel<<<512, 256, 0, stream>>>(AO, Wo, (float*)d_out);
}